// Round 4
// baseline (225.408 us; speedup 1.0000x reference)
//
#include <hip/hip_runtime.h>
#include <stdint.h>

#define EMBED 768
#define HD 64
#define SEQ 4096
#define BATCH 4
#define NROW (BATCH * SEQ)   // 16384
#define NBAND (NROW / 64)    // 256 bands of 64 query rows
#define KSPLIT 8

typedef __bf16 bf16x8 __attribute__((ext_vector_type(8)));
typedef __bf16 bf16x4 __attribute__((ext_vector_type(4)));
typedef float f32x4 __attribute__((ext_vector_type(4)));

// ---------------- W -> wT [192][768] bf16 (once, tiny) ----------------
__global__ __launch_bounds__(256)
void wconv_kernel(const float* __restrict__ Wq, const float* __restrict__ Wk,
                  const float* __restrict__ Wv, __bf16* __restrict__ wT) {
    int id = blockIdx.x * 256 + threadIdx.x;   // < 192*768
    int c = id / EMBED, k = id - c * EMBED;
    const float* W = (c < 64) ? Wq : (c < 128) ? Wk : Wv;
    wT[id] = (__bf16)W[(size_t)k * HD + (c & 63)];
}

// ---------------- fused QKV GEMM: register-direct, N-split ----------------
// grid: (NROW/16, 3) x 64 thr. Wave = 16 rows x 64 cols of ONE matrix (q/k/v).
// 3072 waves = 12 waves/CU. A: hidden f32 + cvt; B: wT bf16 (L2-resident).
__global__ __launch_bounds__(64)
void qkv_gemm_kernel(const float* __restrict__ hidden, const __bf16* __restrict__ wT,
                     const float* __restrict__ bq, const float* __restrict__ bk,
                     const float* __restrict__ bv,
                     __bf16* __restrict__ qo, __bf16* __restrict__ ko,
                     __bf16* __restrict__ vto) {
    const int mat = blockIdx.y;
    const int m0  = blockIdx.x * 16;
    const int lane = threadIdx.x, lr = lane & 15, lg = lane >> 4;

    f32x4 acc[4];
    #pragma unroll
    for (int n = 0; n < 4; ++n) acc[n] = (f32x4){0.f, 0.f, 0.f, 0.f};

    const float*  hrow  = hidden + (size_t)(m0 + lr) * EMBED + lg * 8;
    const __bf16* wbase = wT + (size_t)mat * 64 * EMBED + lg * 8;

    for (int k0 = 0; k0 < EMBED; k0 += 64) {
        bf16x8 a[2];
        #pragma unroll
        for (int ks = 0; ks < 2; ++ks) {
            float4 h0 = *(const float4*)(hrow + k0 + ks * 32);
            float4 h1 = *(const float4*)(hrow + k0 + ks * 32 + 4);
            bf16x8 tv;
            tv[0] = (__bf16)h0.x; tv[1] = (__bf16)h0.y; tv[2] = (__bf16)h0.z; tv[3] = (__bf16)h0.w;
            tv[4] = (__bf16)h1.x; tv[5] = (__bf16)h1.y; tv[6] = (__bf16)h1.z; tv[7] = (__bf16)h1.w;
            a[ks] = tv;
        }
        #pragma unroll
        for (int n = 0; n < 4; ++n) {
            #pragma unroll
            for (int ks = 0; ks < 2; ++ks) {
                bf16x8 bb = *(const bf16x8*)(wbase + (size_t)(n * 16 + lr) * EMBED + k0 + ks * 32);
                acc[n] = __builtin_amdgcn_mfma_f32_16x16x32_bf16(a[ks], bb, acc[n], 0, 0, 0);
            }
        }
    }

    const float* bias = (mat == 0) ? bq : (mat == 1) ? bk : bv;
    const int row0 = m0 + lg * 4;   // C/D: row=(lane>>4)*4+r, col=n*16+lr
    if (mat < 2) {
        __bf16* out = (mat == 0) ? qo : ko;
        #pragma unroll
        for (int n = 0; n < 4; ++n) {
            const float bb = bias[n * 16 + lr];
            #pragma unroll
            for (int r = 0; r < 4; ++r)
                out[(size_t)(row0 + r) * HD + n * 16 + lr] = (__bf16)(acc[n][r] + bb);
        }
    } else {
        #pragma unroll
        for (int n = 0; n < 4; ++n) {
            const float bb = bias[n * 16 + lr];
            bf16x4 pv;
            pv[0] = (__bf16)(acc[n][0] + bb);
            pv[1] = (__bf16)(acc[n][1] + bb);
            pv[2] = (__bf16)(acc[n][2] + bb);
            pv[3] = (__bf16)(acc[n][3] + bb);
            *(bf16x4*)&vto[(size_t)(n * 16 + lr) * NROW + row0] = pv;  // 4 consecutive rows
        }
    }
}

// ---------------- causal flash attention, split-K partials ----------------
// grid: NBAND*KSPLIT = 2048 blocks x 256 thr (4 waves). Block = 64-row band x
// one key split; wave = 16 rows. Longest bands first. No __syncthreads
// (per-wave LDS P + lgkmcnt fence). Writes unnormalized O + per-row (m,l).
__global__ __launch_bounds__(256)
void attn_kernel(const __bf16* __restrict__ qg, const __bf16* __restrict__ kg,
                 const __bf16* __restrict__ vtg,
                 float* __restrict__ opart, float* __restrict__ ml) {
    __shared__ __bf16 p_lds[4][16][72];   // per-wave region; 144B stride: 2-way banks

    const int bid = blockIdx.x;
    const int gi  = bid >> 3;            // band index (descending work)
    const int sp  = bid & (KSPLIT - 1);
    const int t   = 63 - (gi >> 2);      // per-batch 64-row band, longest first
    const int b   = gi & 3;
    const int q0b = t * 64;
    const int nkb = q0b + 64;
    const int chunk = ((nkb + 511) >> 9) << 6;   // ceil(nkb/512)*64
    const int kb = sp * chunk;

    const int w    = threadIdx.x >> 6;
    const int lane = threadIdx.x & 63, lr = lane & 15, lg = lane >> 4;
    const int q0 = q0b + w * 16;         // wave's 16 rows
    const int nk = q0 + 16;
    const int ke = (kb + chunk < nk) ? (kb + chunk) : nk;

    float* mlp = ml + ((size_t)gi * KSPLIT + sp) * 128;   // [0..64)=m, [64..128)=l
    const int rb = w * 16 + lg * 4;      // row-in-band base for this thread

    if (kb >= ke) {                      // empty split for this wave: l=0
        if (lr == 0) {
            #pragma unroll
            for (int r = 0; r < 4; ++r) mlp[64 + rb + r] = 0.f;
        }
        return;
    }

    const __bf16* qb = qg  + (size_t)b * SEQ * HD;
    const __bf16* kp = kg  + (size_t)b * SEQ * HD;
    const __bf16* vb = vtg + (size_t)b * SEQ;   // vb[d*NROW + key]

    const bf16x8 qf0 = *(const bf16x8*)&qb[(q0 + lr) * HD + lg * 8];
    const bf16x8 qf1 = *(const bf16x8*)&qb[(q0 + lr) * HD + 32 + lg * 8];

    f32x4 acc[4];
    const f32x4 zero4 = {0.f, 0.f, 0.f, 0.f};
    #pragma unroll
    for (int n = 0; n < 4; ++n) acc[n] = zero4;
    float m[4], lsum[4];
    #pragma unroll
    for (int r = 0; r < 4; ++r) { m[r] = -INFINITY; lsum[r] = 0.f; }

    const float sc = 0.18033688011112042f;  // log2(e)/sqrt(64): softmax in exp2 domain

    for (int kb0 = kb; kb0 < ke; kb0 += 64) {
        f32x4 sj[4];
        #pragma unroll
        for (int j = 0; j < 4; ++j) {
            bf16x8 kf0 = *(const bf16x8*)&kp[(size_t)(kb0 + j * 16 + lr) * HD + lg * 8];
            bf16x8 kf1 = *(const bf16x8*)&kp[(size_t)(kb0 + j * 16 + lr) * HD + 32 + lg * 8];
            f32x4 z = zero4;
            z = __builtin_amdgcn_mfma_f32_16x16x32_bf16(qf0, kf0, z, 0, 0, 0);
            z = __builtin_amdgcn_mfma_f32_16x16x32_bf16(qf1, kf1, z, 0, 0, 0);
            sj[j] = z;
        }

        float tt[4][4];
        #pragma unroll
        for (int j = 0; j < 4; ++j)
            #pragma unroll
            for (int r = 0; r < 4; ++r) tt[j][r] = sj[j][r] * sc;

        if (kb0 + 63 > q0) {  // tile crosses this wave's diagonal: causal mask
            #pragma unroll
            for (int j = 0; j < 4; ++j)
                #pragma unroll
                for (int r = 0; r < 4; ++r)
                    if (kb0 + j * 16 + lr > q0 + lg * 4 + r) tt[j][r] = -1e30f;
        }

        float mx[4];
        #pragma unroll
        for (int r = 0; r < 4; ++r)
            mx[r] = fmaxf(fmaxf(tt[0][r], tt[1][r]), fmaxf(tt[2][r], tt[3][r]));
        #pragma unroll
        for (int off = 1; off < 16; off <<= 1)
            #pragma unroll
            for (int r = 0; r < 4; ++r) mx[r] = fmaxf(mx[r], __shfl_xor(mx[r], off));

        float p[4][4], rs[4], so[4];
        #pragma unroll
        for (int r = 0; r < 4; ++r) {
            const float nm = fmaxf(m[r], mx[r]);
            so[r] = __builtin_exp2f(m[r] - nm);   // m=-inf first iter -> 0
            m[r] = nm;
            float a = 0.f;
            #pragma unroll
            for (int j = 0; j < 4; ++j) { p[j][r] = __builtin_exp2f(tt[j][r] - nm); a += p[j][r]; }
            rs[r] = a;
        }
        #pragma unroll
        for (int off = 1; off < 16; off <<= 1)
            #pragma unroll
            for (int r = 0; r < 4; ++r) rs[r] += __shfl_xor(rs[r], off);
        #pragma unroll
        for (int r = 0; r < 4; ++r) lsum[r] = lsum[r] * so[r] + rs[r];
        #pragma unroll
        for (int n = 0; n < 4; ++n)
            #pragma unroll
            for (int r = 0; r < 4; ++r) acc[n][r] *= so[r];

        // P (16x64) -> per-wave LDS bf16, re-read as A-fragments (fence only)
        #pragma unroll
        for (int j = 0; j < 4; ++j)
            #pragma unroll
            for (int r = 0; r < 4; ++r)
                p_lds[w][lg * 4 + r][j * 16 + lr] = (__bf16)p[j][r];
        asm volatile("s_waitcnt lgkmcnt(0)" ::: "memory");
        const bf16x8 pa0 = *(const bf16x8*)&p_lds[w][lr][lg * 8];
        const bf16x8 pa1 = *(const bf16x8*)&p_lds[w][lr][32 + lg * 8];
        #pragma unroll
        for (int n = 0; n < 4; ++n) {
            bf16x8 vf0 = *(const bf16x8*)&vb[(size_t)(n * 16 + lr) * NROW + kb0 + lg * 8];
            acc[n] = __builtin_amdgcn_mfma_f32_16x16x32_bf16(pa0, vf0, acc[n], 0, 0, 0);
            bf16x8 vf1 = *(const bf16x8*)&vb[(size_t)(n * 16 + lr) * NROW + kb0 + 32 + lg * 8];
            acc[n] = __builtin_amdgcn_mfma_f32_16x16x32_bf16(pa1, vf1, acc[n], 0, 0, 0);
        }
        asm volatile("" ::: "memory");
    }

    // epilogue: unnormalized O partial + per-row m/l
    float* Op = opart + (size_t)(gi * KSPLIT + sp) * (64 * 64);
    #pragma unroll
    for (int n = 0; n < 4; ++n)
        #pragma unroll
        for (int r = 0; r < 4; ++r)
            Op[(size_t)(rb + r) * 64 + n * 16 + lr] = acc[n][r];
    if (lr == 0) {
        #pragma unroll
        for (int r = 0; r < 4; ++r) {
            mlp[rb + r]      = m[r];
            mlp[64 + rb + r] = (m[r] > -1e29f) ? lsum[r] : 0.f;
        }
    }
}

// ---------------- combine split-K partials ----------------
// grid: NROW*HD/256 x 256 thr; one thread per output element.
__global__ __launch_bounds__(256)
void reduce_kernel(const float* __restrict__ opart, const float* __restrict__ ml,
                   float* __restrict__ out) {
    const int e   = blockIdx.x * 256 + threadIdx.x;
    const int col = e & 63;
    const int row = e >> 6;                 // global row = b*SEQ + sq
    const int b   = row >> 12;
    const int sq  = row & (SEQ - 1);
    const int t   = sq >> 6;
    const int gi  = (63 - t) * 4 + b;
    const int r64 = sq & 63;
    const int nkb = (t + 1) * 64;
    const int chunk = ((nkb + 511) >> 9) << 6;
    const int nsp   = (nkb + chunk - 1) / chunk;

    float M = -INFINITY, ls = 0.f, o = 0.f;
    for (int sp = 0; sp < nsp; ++sp) {
        const size_t base = (size_t)gi * KSPLIT + sp;
        const float lv = ml[base * 128 + 64 + r64];
        if (lv > 0.f) {
            const float mv = ml[base * 128 + r64];
            const float nm = fmaxf(M, mv);
            const float f0 = __builtin_exp2f(M - nm);   // M=-inf first -> 0
            const float f1 = __builtin_exp2f(mv - nm);
            const float ov = opart[base * (64 * 64) + (size_t)r64 * 64 + col];
            o  = o * f0 + f1 * ov;
            ls = ls * f0 + f1 * lv;
            M = nm;
        }
    }
    out[e] = o / ls;
}

extern "C" void kernel_launch(void* const* d_in, const int* in_sizes, int n_in,
                              void* d_out, int out_size, void* d_ws, size_t ws_size,
                              hipStream_t stream) {
    const float* hidden = (const float*)d_in[0];
    const float* Wq = (const float*)d_in[1];
    const float* bq = (const float*)d_in[2];
    const float* Wk = (const float*)d_in[3];
    const float* bk = (const float*)d_in[4];
    const float* Wv = (const float*)d_in[5];
    const float* bv = (const float*)d_in[6];

    __bf16* qbuf  = (__bf16*)d_ws;                     // [NROW][64]
    __bf16* kbuf  = qbuf + (size_t)NROW * HD;          // [NROW][64]
    __bf16* vtbuf = kbuf + (size_t)NROW * HD;          // [64][NROW] (V transposed)
    __bf16* wT    = vtbuf + (size_t)NROW * HD;         // [192][768]
    float*  opart = (float*)(wT + (size_t)192 * EMBED);            // [NBAND*KSPLIT][64][64]
    float*  ml    = opart + (size_t)NBAND * KSPLIT * 64 * 64;      // [NBAND*KSPLIT][128]

    wconv_kernel<<<(192 * EMBED) / 256, 256, 0, stream>>>(Wq, Wk, Wv, wT);

    qkv_gemm_kernel<<<dim3(NROW / 16, 3), 64, 0, stream>>>(
        hidden, wT, bq, bk, bv, qbuf, kbuf, vtbuf);

    attn_kernel<<<NBAND * KSPLIT, 256, 0, stream>>>(
        qbuf, kbuf, vtbuf, opart, ml);

    reduce_kernel<<<(NROW * HD) / 256, 256, 0, stream>>>(opart, ml, (float*)d_out);
}